// Round 14
// baseline (9814.787 us; speedup 1.0000x reference)
//
#include <hip/hip_runtime.h>
#include <stdint.h>

// ---------------------------------------------------------------------------
// Persistent-RNN 2-layer LSTM decoder (B=64,H=1024,OUT=512,SEQ=256), MI355X.
// R14 = R12 (symmetric hops: distributed FC 2 dims/block, rotating
// write-once buffers, cached reads) with ONE mechanism change:
//  * hops 2 (fh1) and 3 (fy) lose their leader relay — every block scans
//    the 256-flag row directly (starts at its own publish; ~2-3 poll
//    rounds). Removes one serial L3 round trip + relay jitter per hop.
//  * hop 1 (fh0) keeps the leader relay: it is p1-filled, so followers
//    poll a single epoch word during useful work (relay is right there).
// Everything else byte-identical to R12 (best: 4.92 ms).
// ---------------------------------------------------------------------------

#define NBLK 256
#define NTHR 256
#define HDIM 1024
#define ODIM 512
#define BDIM 64
#define SEQL 256

typedef _Float16 v8h __attribute__((ext_vector_type(8)));
typedef float    v4f __attribute__((ext_vector_type(4)));

// LDS: per k-slice, 64 lanes x 16B contiguous = 1024B (conflict-free b128)
#define WL0_NS 48
#define WL1_NS 64
#define WFC_NS 32
#define WL0_OFF 0
#define WL1_OFF (WL0_NS*1024)
#define WFC_OFF (WL1_OFF + WL1_NS*1024)
#define SMEM_BYTES (WFC_OFF + WFC_NS*1024)   // 147456 B

#define YB_SZ  (BDIM*ODIM*2)            // 64 KB per slot
#define HB_SZ  (BDIM*HDIM*2)            // 128 KB per slot

// flags: fh0[4][256], fh1[4][256], fy[4][256] packed 4B
// epochs: eh0 [(wv,f)] one word, 64B stride (hop-1 relay only).
#define FH0_REL 0
#define FH1_REL (4*256*4)
#define FY_REL  (FH1_REL + 4*256*4)
#define EH0_REL (FY_REL + 4*256*4)
#define FLG_BYTES (EH0_REL + 4*8*64)

__device__ __forceinline__ float fsig(float x)   { return 1.0f / (1.0f + __expf(-x)); }
__device__ __forceinline__ float ftanhf(float x) { return 1.0f - 2.0f / (__expf(2.0f*x) + 1.0f); }

__device__ __forceinline__ unsigned long long ald8(const void* p){
  return __hip_atomic_load((const unsigned long long*)p, __ATOMIC_RELAXED, __HIP_MEMORY_SCOPE_AGENT);
}
__device__ __forceinline__ unsigned int ald4(const void* p){
  return __hip_atomic_load((const unsigned int*)p, __ATOMIC_RELAXED, __HIP_MEMORY_SCOPE_AGENT);
}
__device__ __forceinline__ void ast4(void* p, unsigned int v){
  __hip_atomic_store((unsigned int*)p, v, __ATOMIC_RELAXED, __HIP_MEMORY_SCOPE_AGENT);
}

// wrap-acquire: once per D steps — drop last-epoch clean L2 lines.
__device__ __forceinline__ void wrap_inv(){
  asm volatile("s_waitcnt vmcnt(0)\n\tbuffer_inv sc1" ::: "memory");
}

// follower: poll one epoch word with light sleep (hop-1 relay)
__device__ __forceinline__ void wait_word(const unsigned int* w, unsigned int tag){
  while (ald4(w) < tag) __builtin_amdgcn_s_sleep(1);
  asm volatile("" ::: "memory");
}

// direct scan of a 256-flag row (4 flags/lane) — no relay
__device__ __forceinline__ void scan256(const unsigned int* rowf, unsigned int tag){
  const char* p = (const char*)(rowf + (threadIdx.x & 63)*4);
  while (true){
    unsigned long long a = ald8(p);
    unsigned long long b = ald8(p+8);
    unsigned int m0 = (unsigned int)a, m1 = (unsigned int)(a >> 32);
    unsigned int m2 = (unsigned int)b, m3 = (unsigned int)(b >> 32);
    unsigned int m = min(min(m0, m1), min(m2, m3));
    if (__all(m >= tag)) break;
    __builtin_amdgcn_s_sleep(1);
  }
  asm volatile("" ::: "memory");
}

// leader: scan full 256-flag row, then store epoch word (hop-1 only)
__device__ __forceinline__ void scan256_pub(const unsigned int* rowf, unsigned int* ew,
                                            unsigned int tag){
  const char* p = (const char*)(rowf + (threadIdx.x & 63)*4);
  while (true){
    unsigned long long a = ald8(p);
    unsigned long long b = ald8(p+8);
    unsigned int m0 = (unsigned int)a, m1 = (unsigned int)(a >> 32);
    unsigned int m2 = (unsigned int)b, m3 = (unsigned int)(b >> 32);
    unsigned int m = min(min(m0, m1), min(m2, m3));
    if (__all(m >= tag)) break;
    __builtin_amdgcn_s_sleep(1);
  }
  if ((threadIdx.x & 63) == 0) ast4(ew, tag);
  asm volatile("" ::: "memory");
}

// wave publish: drain this wave's vmem (reads+writes), store tag (1 writer).
__device__ __forceinline__ void publish(unsigned int* flag, unsigned int tag){
  asm volatile("s_waitcnt vmcnt(0)" ::: "memory");
  if ((threadIdx.x & 63) == 0) ast4(flag, tag);
}

// K-loop: NC chunks of 256 K-cols (8 MFMAs each); A via normal cached loads.
template<int NC>
__device__ __forceinline__ v4f gemm_phase(const char* const cb[], const char* wl, v4f acc){
  v8h A[4][8];
  constexpr int PF = (NC < 3) ? NC : 3;
  #pragma unroll
  for (int p = 0; p < PF; p++){
    #pragma unroll
    for (int j = 0; j < 8; j++) A[p][j] = *(const v8h*)(cb[p] + (size_t)j*64);
  }
  #pragma unroll
  for (int c = 0; c < NC; c++){
    const int cur = c & 3, nx = (c + 3) & 3;
    if (c + 3 < NC){
      #pragma unroll
      for (int j = 0; j < 8; j++) A[nx][j] = *(const v8h*)(cb[c+3] + (size_t)j*64);
    }
    #pragma unroll
    for (int j = 0; j < 8; j++){
      v8h B = *(const v8h*)(wl + (size_t)(c*8 + j)*1024);
      acc = __builtin_amdgcn_mfma_f32_16x16x32_f16(A[cur][j], B, acc, 0, 0, 0);
    }
  }
  return acc;
}

// Same A-stream feeding two B matrices (L1 input-part + next-step L0 recurrent).
__device__ __forceinline__ void gemm_dual4(const char* const cb[], const char* wlA,
                                           const char* wlB, v4f& accA, v4f& accB){
  v8h A[4][8];
  #pragma unroll
  for (int p = 0; p < 3; p++){
    #pragma unroll
    for (int j = 0; j < 8; j++) A[p][j] = *(const v8h*)(cb[p] + (size_t)j*64);
  }
  #pragma unroll
  for (int c = 0; c < 4; c++){
    const int cur = c & 3, nx = (c + 3) & 3;
    if (c + 3 < 4){
      #pragma unroll
      for (int j = 0; j < 8; j++) A[nx][j] = *(const v8h*)(cb[c+3] + (size_t)j*64);
    }
    #pragma unroll
    for (int j = 0; j < 8; j++){
      v8h BA = *(const v8h*)(wlA + (size_t)(c*8 + j)*1024);
      accA = __builtin_amdgcn_mfma_f32_16x16x32_f16(A[cur][j], BA, accA, 0, 0, 0);
      v8h BB = *(const v8h*)(wlB + (size_t)(c*8 + j)*1024);
      accB = __builtin_amdgcn_mfma_f32_16x16x32_f16(A[cur][j], BB, accB, 0, 0, 0);
    }
  }
}

// LSTM epilogue: gate gather via xor1/2/3; h packed 4 units -> one 8B sc1 store.
__device__ __forceinline__ void lstm_epi_pack(v4f acc, float bias, float* cs,
                                              char* hbase, int l15, int gidx){
  #pragma unroll
  for (int r = 0; r < 4; r++){
    float v  = acc[r] + bias;
    float x1 = __shfl_xor(v, 1);
    float x2 = __shfl_xor(v, 2);
    float x3 = __shfl_xor(v, 3);
    float vi = (gidx==0)?v :(gidx==1)?x1:(gidx==2)?x2:x3;
    float vf = (gidx==1)?v :(gidx==0)?x1:(gidx==3)?x2:x3;
    float vg = (gidx==2)?v :(gidx==3)?x1:(gidx==0)?x2:x3;
    float vo = (gidx==3)?v :(gidx==2)?x1:(gidx==1)?x2:x3;
    float ii = fsig(vi), ff = fsig(vf), gg = ftanhf(vg), oo = fsig(vo);
    float cn = ff*cs[r] + ii*gg;
    cs[r] = cn;
    float hn = oo * ftanhf(cn);
    unsigned int uv = (unsigned int)__builtin_bit_cast(unsigned short, (_Float16)hn);
    unsigned int o4 = (unsigned int)__shfl_xor((int)uv, 4);
    unsigned int pr = uv | (o4 << 16);
    unsigned int o8 = (unsigned int)__shfl_xor((int)pr, 8);
    if (l15 == 0){
      unsigned long long full = (unsigned long long)pr | ((unsigned long long)o8 << 32);
      __hip_atomic_store((unsigned long long*)(hbase + (size_t)r*(HDIM*2)), full,
                         __ATOMIC_RELAXED, __HIP_MEMORY_SCOPE_AGENT);
    }
  }
}

__global__ void init_kernel(const float* __restrict__ h0,
                            _Float16* __restrict__ h0bi, _Float16* __restrict__ h1bi,
                            _Float16* __restrict__ ybi){
  int i = blockIdx.x*256 + threadIdx.x;
  if (i < BDIM*HDIM){
    h0bi[i] = (_Float16)h0[i];
    h1bi[i] = (_Float16)h0[BDIM*HDIM + i];
  }
  if (i < BDIM*ODIM) ybi[i] = (_Float16)(-2.0f); // SOS
}

__launch_bounds__(NTHR, 1)
__global__ void decoder_kernel(
    const float* __restrict__ Wih0, const float* __restrict__ Whh0,
    const float* __restrict__ bih0, const float* __restrict__ bhh0,
    const float* __restrict__ Wih1, const float* __restrict__ Whh1,
    const float* __restrict__ bih1, const float* __restrict__ bhh1,
    const float* __restrict__ Wfc,  const float* __restrict__ bfc,
    const float* __restrict__ c0in, float* __restrict__ out,
    char* __restrict__ yB, char* __restrict__ h0B, char* __restrict__ h1B,
    char* __restrict__ flg, int dmask)
{
  extern __shared__ char smem[];
  const int bid = blockIdx.x;
  const int tid = threadIdx.x;
  const int wv  = tid >> 6;
  const int ln  = tid & 63;
  const int l15 = ln & 15;
  const int lq  = ln >> 4;
  const int u0  = bid * 4;
  const int f   = bid & 7;
  const int lead_h0 = (bid < 8);

  unsigned int* fh0r = (unsigned int*)(flg + FH0_REL) + wv*256;
  unsigned int* fh1r = (unsigned int*)(flg + FH1_REL) + wv*256;
  unsigned int* fyr  = (unsigned int*)(flg + FY_REL)  + wv*256;
  unsigned int* eh0  = (unsigned int*)(flg + EH0_REL + (wv*8 + f)*64);

  // ---- one-time: weights fp32->fp16 into LDS, exact fragment order ----
  for (int slot = tid; slot < WL0_NS*64; slot += NTHR){
    int s = slot >> 6, l = slot & 63;
    int r16 = l & 15, q = l >> 4;
    int grow = (r16 & 3)*HDIM + u0 + (r16 >> 2);
    int kb = s*32 + q*8;
    const float* src; int k0;
    if (kb < ODIM){ src = Wih0 + (size_t)grow*ODIM; k0 = kb; }
    else          { src = Whh0 + (size_t)grow*HDIM; k0 = kb - ODIM; }
    v8h hv;
    #pragma unroll
    for (int j = 0; j < 8; j++) hv[j] = (_Float16)src[k0 + j];
    *(v8h*)(smem + WL0_OFF + s*1024 + l*16) = hv;
  }
  for (int slot = tid; slot < WL1_NS*64; slot += NTHR){
    int s = slot >> 6, l = slot & 63;
    int r16 = l & 15, q = l >> 4;
    int grow = (r16 & 3)*HDIM + u0 + (r16 >> 2);
    int kb = s*32 + q*8;
    const float* src; int k0;
    if (kb < HDIM){ src = Wih1 + (size_t)grow*HDIM; k0 = kb; }
    else          { src = Whh1 + (size_t)grow*HDIM; k0 = kb - HDIM; }
    v8h hv;
    #pragma unroll
    for (int j = 0; j < 8; j++) hv[j] = (_Float16)src[k0 + j];
    *(v8h*)(smem + WL1_OFF + s*1024 + l*16) = hv;
  }
  // FC tile: rows 0..1 = dims 2*bid, 2*bid+1; rows 2..15 zero (all blocks)
  for (int slot = tid; slot < WFC_NS*64; slot += NTHR){
    int s = slot >> 6, l = slot & 63;
    int r16 = l & 15, q = l >> 4;
    int k0 = s*32 + q*8;
    v8h hv;
    if (r16 < 2){
      const float* src = Wfc + (size_t)(bid*2 + r16)*HDIM;
      #pragma unroll
      for (int j = 0; j < 8; j++) hv[j] = (_Float16)src[k0 + j];
    } else {
      #pragma unroll
      for (int j = 0; j < 8; j++) hv[j] = (_Float16)0.0f;
    }
    *(v8h*)(smem + WFC_OFF + s*1024 + l*16) = hv;
  }
  __syncthreads();   // LDS weights ready (only barrier in the kernel)

  // ---- per-lane constants ----
  const int gidx = l15 & 3;
  const int unit = u0 + (l15 >> 2);
  const int growL = gidx*HDIM + unit;
  const float bias0 = bih0[growL] + bhh0[growL];
  const float bias1 = bih1[growL] + bhh1[growL];
  const float biasf = (l15 < 2) ? bfc[bid*2 + l15] : 0.f;

  const int rb = wv*16 + lq*4;
  float cs0[4], cs1[4];
  #pragma unroll
  for (int r = 0; r < 4; r++){
    int b = rb + r;
    cs0[r] = c0in[(size_t)(0*BDIM + b)*HDIM + unit];
    cs1[r] = c0in[(size_t)(1*BDIM + b)*HDIM + unit];
  }

  const int row = wv*16 + l15;
  const size_t aoffY = (size_t)row*ODIM*2 + (size_t)lq*16;
  const size_t aoffH = (size_t)row*HDIM*2 + (size_t)lq*16;
  const size_t hwoff = ((size_t)rb*HDIM + u0)*2;
  const char* wl0 = smem + WL0_OFF + ln*16;
  const char* wl1 = smem + WL1_OFF + ln*16;
  const char* wlf = smem + WFC_OFF + ln*16;
  const char* wl0r = wl0 + 16*1024;   // Whh0 slices
  const char* wl1r = wl1 + 32*1024;   // Whh1 slices

  // prologue: p0 = Whh0 @ h0_init
  v4f p0 = {0.f,0.f,0.f,0.f};
  {
    const char* hi = h0B + (size_t)dmask*HB_SZ + aoffH;
    const char* cb[4] = { hi, hi+512, hi+1024, hi+1536 };
    p0 = gemm_phase<4>(cb, wl0r, p0);
  }

  for (int t = 0; t < SEQL; t++){
    const int sp = (t - 1) & dmask;
    const int sc = t & dmask;

    if ((t & dmask) == 0) wrap_inv();  // once per rotation epoch

    // -- hop3 tail: y[t-1] ready? DIRECT scan (no relay)
    if (t > 0) scan256(fyr, (unsigned)t);

    // -- L0 input part (K=512) + recurrent partial -> h0[t]
    {
      const char* ysrc = yB + (size_t)sp*YB_SZ + aoffY;
      const char* cb[2] = { ysrc, ysrc+512 };
      v4f acc = gemm_phase<2>(cb, wl0, p0);
      lstm_epi_pack(acc, bias0, cs0, h0B + (size_t)sc*HB_SZ + hwoff, l15, gidx);
    }
    publish(&fh0r[bid], (unsigned)(t+1));

    // -- p1 = Whh1 @ h1[t-1] (fills the eh0 wait), then hop1 rendezvous
    v4f p1 = {0.f,0.f,0.f,0.f};
    {
      const char* hs = h1B + (size_t)sp*HB_SZ + aoffH;
      const char* cb[4] = { hs, hs+512, hs+1024, hs+1536 };
      p1 = gemm_phase<4>(cb, wl1r, p1);
      if (lead_h0) scan256_pub(fh0r, eh0, (unsigned)(t+1));
      else         wait_word(eh0, (unsigned)(t+1));
    }

    // -- L1 input part + fused next-step L0 recurrent (shared A) -> h1[t]
    {
      const char* hs = h0B + (size_t)sc*HB_SZ + aoffH;
      const char* cb[4] = { hs, hs+512, hs+1024, hs+1536 };
      v4f np0 = {0.f,0.f,0.f,0.f};
      gemm_dual4(cb, wl1, wl0r, p1, np0);
      lstm_epi_pack(p1, bias1, cs1, h1B + (size_t)sc*HB_SZ + hwoff, l15, gidx);
      p0 = np0;
    }
    publish(&fh1r[bid], (unsigned)(t+1));

    // -- hop2: h1[t] ready? DIRECT scan (no relay)
    scan256(fh1r, (unsigned)(t+1));

    // -- FC (all blocks, 2 dims each): y[t] cols 2*bid..2*bid+1
    {
      const char* f1 = h1B + (size_t)sc*HB_SZ + aoffH;
      const char* cb[4] = { f1, f1+512, f1+1024, f1+1536 };
      v4f acc = {0.f,0.f,0.f,0.f};
      acc = gemm_phase<4>(cb, wlf, acc);
      char* ydst = yB + (size_t)sc*YB_SZ;
      #pragma unroll
      for (int r = 0; r < 4; r++){
        float v = fmaxf(acc[r] + biasf, 0.f);
        int b = rb + r;
        // y fp16 pair store (dims 2*bid, 2*bid+1) by l15==0 lanes
        unsigned int uv = (unsigned int)__builtin_bit_cast(unsigned short, (_Float16)v);
        unsigned int o1 = (unsigned int)__shfl_xor((int)uv, 1);
        if (l15 == 0){
          unsigned int pr = uv | (o1 << 16);
          ast4(ydst + ((size_t)b*ODIM + bid*2)*2, pr);
        }
        // out float store (2 lanes per row)
        if (l15 < 2) out[((size_t)b*SEQL + t)*ODIM + bid*2 + l15] = v;
      }
    }
    publish(&fyr[bid], (unsigned)(t+1));
  }
}

extern "C" void kernel_launch(void* const* d_in, const int* in_sizes, int n_in,
                              void* d_out, int out_size, void* d_ws, size_t ws_size,
                              hipStream_t stream){
  (void)in_sizes; (void)n_in; (void)out_size;

  int D = 16;
  while (D > 2 && (size_t)D*(YB_SZ + 2*HB_SZ) + FLG_BYTES > ws_size) D >>= 1;
  if ((size_t)D*(YB_SZ + 2*HB_SZ) + FLG_BYTES > ws_size) return;

  char* ws  = (char*)d_ws;
  char* yB  = ws;
  char* h0B = yB + (size_t)D*YB_SZ;
  char* h1B = h0B + (size_t)D*HB_SZ;
  char* flg = h1B + (size_t)D*HB_SZ;

  const float* h0   = (const float*)d_in[1];
  const float* c0   = (const float*)d_in[2];
  const float* Wih0 = (const float*)d_in[3];
  const float* Whh0 = (const float*)d_in[4];
  const float* bih0 = (const float*)d_in[5];
  const float* bhh0 = (const float*)d_in[6];
  const float* Wih1 = (const float*)d_in[7];
  const float* Whh1 = (const float*)d_in[8];
  const float* bih1 = (const float*)d_in[9];
  const float* bhh1 = (const float*)d_in[10];
  const float* Wfc  = (const float*)d_in[11];
  const float* bfc  = (const float*)d_in[12];
  float* out = (float*)d_out;

  (void)hipMemsetAsync(flg, 0, FLG_BYTES, stream);
  hipLaunchKernelGGL(init_kernel, dim3(256), dim3(256), 0, stream,
                     h0,
                     (_Float16*)(h0B + (size_t)(D-1)*HB_SZ),
                     (_Float16*)(h1B + (size_t)(D-1)*HB_SZ),
                     (_Float16*)(yB  + (size_t)(D-1)*YB_SZ));

  (void)hipFuncSetAttribute((const void*)decoder_kernel,
                            hipFuncAttributeMaxDynamicSharedMemorySize, SMEM_BYTES);
  hipLaunchKernelGGL(decoder_kernel, dim3(NBLK), dim3(NTHR), SMEM_BYTES, stream,
                     Wih0, Whh0, bih0, bhh0, Wih1, Whh1, bih1, bhh1,
                     Wfc, bfc, c0, out, yB, h0B, h1B, flg, D - 1);
}

// Round 15
// 5829.792 us; speedup vs baseline: 1.6836x; 1.6836x over previous
//
#include <hip/hip_runtime.h>
#include <stdint.h>

// ---------------------------------------------------------------------------
// Persistent-RNN 2-layer LSTM decoder (B=64,H=1024,OUT=512,SEQ=256), MI355X.
// R15 = R12 (symmetric hops, distributed FC 2 dims/block, rotating
// write-once buffers, cached reads, leader relays) + ONE legal filler move:
//  * dual gemm split: publish fh1 right after the L1-input part.
//  * np0 (next-step L0 recurrent) parked in the eh1 window: followers
//    compute np0 then poll; lead_h1 relays FIRST then computes np0 (its
//    detection advantage absorbs it — R13's bug was scanning AFTER np0).
//  * out stores after the fy publish (consumed by nobody).
// R14 lesson kept: leader relay everywhere; no direct 256-scans by all.
// ---------------------------------------------------------------------------

#define NBLK 256
#define NTHR 256
#define HDIM 1024
#define ODIM 512
#define BDIM 64
#define SEQL 256

typedef _Float16 v8h __attribute__((ext_vector_type(8)));
typedef float    v4f __attribute__((ext_vector_type(4)));

// LDS: per k-slice, 64 lanes x 16B contiguous = 1024B (conflict-free b128)
#define WL0_NS 48
#define WL1_NS 64
#define WFC_NS 32
#define WL0_OFF 0
#define WL1_OFF (WL0_NS*1024)
#define WFC_OFF (WL1_OFF + WL1_NS*1024)
#define SMEM_BYTES (WFC_OFF + WFC_NS*1024)   // 147456 B

#define YB_SZ  (BDIM*ODIM*2)            // 64 KB per slot
#define HB_SZ  (BDIM*HDIM*2)            // 128 KB per slot

// flags: fh0[4][256], fh1[4][256], fy[4][256] packed 4B
// epochs: eh0/eh1/ey [(wv,f)] one word each, 64B stride.
#define FH0_REL 0
#define FH1_REL (4*256*4)
#define FY_REL  (FH1_REL + 4*256*4)
#define EH0_REL (FY_REL + 4*256*4)
#define EH1_REL (EH0_REL + 4*8*64)
#define EY_REL  (EH1_REL + 4*8*64)
#define FLG_BYTES (EY_REL + 4*8*64)

__device__ __forceinline__ float fsig(float x)   { return 1.0f / (1.0f + __expf(-x)); }
__device__ __forceinline__ float ftanhf(float x) { return 1.0f - 2.0f / (__expf(2.0f*x) + 1.0f); }

__device__ __forceinline__ unsigned long long ald8(const void* p){
  return __hip_atomic_load((const unsigned long long*)p, __ATOMIC_RELAXED, __HIP_MEMORY_SCOPE_AGENT);
}
__device__ __forceinline__ unsigned int ald4(const void* p){
  return __hip_atomic_load((const unsigned int*)p, __ATOMIC_RELAXED, __HIP_MEMORY_SCOPE_AGENT);
}
__device__ __forceinline__ void ast4(void* p, unsigned int v){
  __hip_atomic_store((unsigned int*)p, v, __ATOMIC_RELAXED, __HIP_MEMORY_SCOPE_AGENT);
}

// wrap-acquire: once per D steps — drop last-epoch clean L2 lines.
__device__ __forceinline__ void wrap_inv(){
  asm volatile("s_waitcnt vmcnt(0)\n\tbuffer_inv sc1" ::: "memory");
}

// follower: poll one epoch word with light sleep
__device__ __forceinline__ void wait_word(const unsigned int* w, unsigned int tag){
  while (ald4(w) < tag) __builtin_amdgcn_s_sleep(1);
  asm volatile("" ::: "memory");
}

// leader: scan full 256-flag row (4 flags/lane), then store epoch word
__device__ __forceinline__ void scan256_pub(const unsigned int* rowf, unsigned int* ew,
                                            unsigned int tag){
  const char* p = (const char*)(rowf + (threadIdx.x & 63)*4);
  while (true){
    unsigned long long a = ald8(p);
    unsigned long long b = ald8(p+8);
    unsigned int m0 = (unsigned int)a, m1 = (unsigned int)(a >> 32);
    unsigned int m2 = (unsigned int)b, m3 = (unsigned int)(b >> 32);
    unsigned int m = min(min(m0, m1), min(m2, m3));
    if (__all(m >= tag)) break;
    __builtin_amdgcn_s_sleep(1);
  }
  if ((threadIdx.x & 63) == 0) ast4(ew, tag);
  asm volatile("" ::: "memory");
}

// wave publish: drain this wave's vmem (reads+writes), store tag (1 writer).
__device__ __forceinline__ void publish(unsigned int* flag, unsigned int tag){
  asm volatile("s_waitcnt vmcnt(0)" ::: "memory");
  if ((threadIdx.x & 63) == 0) ast4(flag, tag);
}

// K-loop: NC chunks of 256 K-cols (8 MFMAs each); A via normal cached loads.
template<int NC>
__device__ __forceinline__ v4f gemm_phase(const char* const cb[], const char* wl, v4f acc){
  v8h A[4][8];
  constexpr int PF = (NC < 3) ? NC : 3;
  #pragma unroll
  for (int p = 0; p < PF; p++){
    #pragma unroll
    for (int j = 0; j < 8; j++) A[p][j] = *(const v8h*)(cb[p] + (size_t)j*64);
  }
  #pragma unroll
  for (int c = 0; c < NC; c++){
    const int cur = c & 3, nx = (c + 3) & 3;
    if (c + 3 < NC){
      #pragma unroll
      for (int j = 0; j < 8; j++) A[nx][j] = *(const v8h*)(cb[c+3] + (size_t)j*64);
    }
    #pragma unroll
    for (int j = 0; j < 8; j++){
      v8h B = *(const v8h*)(wl + (size_t)(c*8 + j)*1024);
      acc = __builtin_amdgcn_mfma_f32_16x16x32_f16(A[cur][j], B, acc, 0, 0, 0);
    }
  }
  return acc;
}

// LSTM epilogue: gate gather via xor1/2/3; h packed 4 units -> one 8B sc1 store.
__device__ __forceinline__ void lstm_epi_pack(v4f acc, float bias, float* cs,
                                              char* hbase, int l15, int gidx){
  #pragma unroll
  for (int r = 0; r < 4; r++){
    float v  = acc[r] + bias;
    float x1 = __shfl_xor(v, 1);
    float x2 = __shfl_xor(v, 2);
    float x3 = __shfl_xor(v, 3);
    float vi = (gidx==0)?v :(gidx==1)?x1:(gidx==2)?x2:x3;
    float vf = (gidx==1)?v :(gidx==0)?x1:(gidx==3)?x2:x3;
    float vg = (gidx==2)?v :(gidx==3)?x1:(gidx==0)?x2:x3;
    float vo = (gidx==3)?v :(gidx==2)?x1:(gidx==1)?x2:x3;
    float ii = fsig(vi), ff = fsig(vf), gg = ftanhf(vg), oo = fsig(vo);
    float cn = ff*cs[r] + ii*gg;
    cs[r] = cn;
    float hn = oo * ftanhf(cn);
    unsigned int uv = (unsigned int)__builtin_bit_cast(unsigned short, (_Float16)hn);
    unsigned int o4 = (unsigned int)__shfl_xor((int)uv, 4);
    unsigned int pr = uv | (o4 << 16);
    unsigned int o8 = (unsigned int)__shfl_xor((int)pr, 8);
    if (l15 == 0){
      unsigned long long full = (unsigned long long)pr | ((unsigned long long)o8 << 32);
      __hip_atomic_store((unsigned long long*)(hbase + (size_t)r*(HDIM*2)), full,
                         __ATOMIC_RELAXED, __HIP_MEMORY_SCOPE_AGENT);
    }
  }
}

__global__ void init_kernel(const float* __restrict__ h0,
                            _Float16* __restrict__ h0bi, _Float16* __restrict__ h1bi,
                            _Float16* __restrict__ ybi){
  int i = blockIdx.x*256 + threadIdx.x;
  if (i < BDIM*HDIM){
    h0bi[i] = (_Float16)h0[i];
    h1bi[i] = (_Float16)h0[BDIM*HDIM + i];
  }
  if (i < BDIM*ODIM) ybi[i] = (_Float16)(-2.0f); // SOS
}

__launch_bounds__(NTHR, 1)
__global__ void decoder_kernel(
    const float* __restrict__ Wih0, const float* __restrict__ Whh0,
    const float* __restrict__ bih0, const float* __restrict__ bhh0,
    const float* __restrict__ Wih1, const float* __restrict__ Whh1,
    const float* __restrict__ bih1, const float* __restrict__ bhh1,
    const float* __restrict__ Wfc,  const float* __restrict__ bfc,
    const float* __restrict__ c0in, float* __restrict__ out,
    char* __restrict__ yB, char* __restrict__ h0B, char* __restrict__ h1B,
    char* __restrict__ flg, int dmask)
{
  extern __shared__ char smem[];
  const int bid = blockIdx.x;
  const int tid = threadIdx.x;
  const int wv  = tid >> 6;
  const int ln  = tid & 63;
  const int l15 = ln & 15;
  const int lq  = ln >> 4;
  const int u0  = bid * 4;
  const int f   = bid & 7;
  const int lead_h0 = (bid < 8);
  const int lead_h1 = (bid >= 8  && bid < 16);
  const int lead_y  = (bid >= 16 && bid < 24);

  unsigned int* fh0r = (unsigned int*)(flg + FH0_REL) + wv*256;
  unsigned int* fh1r = (unsigned int*)(flg + FH1_REL) + wv*256;
  unsigned int* fyr  = (unsigned int*)(flg + FY_REL)  + wv*256;
  unsigned int* eh0  = (unsigned int*)(flg + EH0_REL + (wv*8 + f)*64);
  unsigned int* eh1  = (unsigned int*)(flg + EH1_REL + (wv*8 + f)*64);
  unsigned int* ey   = (unsigned int*)(flg + EY_REL  + (wv*8 + f)*64);

  // ---- one-time: weights fp32->fp16 into LDS, exact fragment order ----
  for (int slot = tid; slot < WL0_NS*64; slot += NTHR){
    int s = slot >> 6, l = slot & 63;
    int r16 = l & 15, q = l >> 4;
    int grow = (r16 & 3)*HDIM + u0 + (r16 >> 2);
    int kb = s*32 + q*8;
    const float* src; int k0;
    if (kb < ODIM){ src = Wih0 + (size_t)grow*ODIM; k0 = kb; }
    else          { src = Whh0 + (size_t)grow*HDIM; k0 = kb - ODIM; }
    v8h hv;
    #pragma unroll
    for (int j = 0; j < 8; j++) hv[j] = (_Float16)src[k0 + j];
    *(v8h*)(smem + WL0_OFF + s*1024 + l*16) = hv;
  }
  for (int slot = tid; slot < WL1_NS*64; slot += NTHR){
    int s = slot >> 6, l = slot & 63;
    int r16 = l & 15, q = l >> 4;
    int grow = (r16 & 3)*HDIM + u0 + (r16 >> 2);
    int kb = s*32 + q*8;
    const float* src; int k0;
    if (kb < HDIM){ src = Wih1 + (size_t)grow*HDIM; k0 = kb; }
    else          { src = Whh1 + (size_t)grow*HDIM; k0 = kb - HDIM; }
    v8h hv;
    #pragma unroll
    for (int j = 0; j < 8; j++) hv[j] = (_Float16)src[k0 + j];
    *(v8h*)(smem + WL1_OFF + s*1024 + l*16) = hv;
  }
  // FC tile: rows 0..1 = dims 2*bid, 2*bid+1; rows 2..15 zero (all blocks)
  for (int slot = tid; slot < WFC_NS*64; slot += NTHR){
    int s = slot >> 6, l = slot & 63;
    int r16 = l & 15, q = l >> 4;
    int k0 = s*32 + q*8;
    v8h hv;
    if (r16 < 2){
      const float* src = Wfc + (size_t)(bid*2 + r16)*HDIM;
      #pragma unroll
      for (int j = 0; j < 8; j++) hv[j] = (_Float16)src[k0 + j];
    } else {
      #pragma unroll
      for (int j = 0; j < 8; j++) hv[j] = (_Float16)0.0f;
    }
    *(v8h*)(smem + WFC_OFF + s*1024 + l*16) = hv;
  }
  __syncthreads();   // LDS weights ready (only barrier in the kernel)

  // ---- per-lane constants ----
  const int gidx = l15 & 3;
  const int unit = u0 + (l15 >> 2);
  const int growL = gidx*HDIM + unit;
  const float bias0 = bih0[growL] + bhh0[growL];
  const float bias1 = bih1[growL] + bhh1[growL];
  const float biasf = (l15 < 2) ? bfc[bid*2 + l15] : 0.f;

  const int rb = wv*16 + lq*4;
  float cs0[4], cs1[4];
  #pragma unroll
  for (int r = 0; r < 4; r++){
    int b = rb + r;
    cs0[r] = c0in[(size_t)(0*BDIM + b)*HDIM + unit];
    cs1[r] = c0in[(size_t)(1*BDIM + b)*HDIM + unit];
  }

  const int row = wv*16 + l15;
  const size_t aoffY = (size_t)row*ODIM*2 + (size_t)lq*16;
  const size_t aoffH = (size_t)row*HDIM*2 + (size_t)lq*16;
  const size_t hwoff = ((size_t)rb*HDIM + u0)*2;
  const char* wl0 = smem + WL0_OFF + ln*16;
  const char* wl1 = smem + WL1_OFF + ln*16;
  const char* wlf = smem + WFC_OFF + ln*16;
  const char* wl0r = wl0 + 16*1024;   // Whh0 slices
  const char* wl1r = wl1 + 32*1024;   // Whh1 slices

  // prologue: p0 = Whh0 @ h0_init
  v4f p0 = {0.f,0.f,0.f,0.f};
  {
    const char* hi = h0B + (size_t)dmask*HB_SZ + aoffH;
    const char* cb[4] = { hi, hi+512, hi+1024, hi+1536 };
    p0 = gemm_phase<4>(cb, wl0r, p0);
  }

  for (int t = 0; t < SEQL; t++){
    const int sp = (t - 1) & dmask;
    const int sc = t & dmask;

    if ((t & dmask) == 0) wrap_inv();  // once per rotation epoch

    // -- hop3 tail: y[t-1] ready? (leaders 16..23 scan fy; others poll ey)
    if (t > 0){
      if (lead_y) scan256_pub(fyr, ey, (unsigned)t);
      else        wait_word(ey, (unsigned)t);
    }

    // -- L0 input part (K=512) + recurrent partial -> h0[t]
    {
      const char* ysrc = yB + (size_t)sp*YB_SZ + aoffY;
      const char* cb[2] = { ysrc, ysrc+512 };
      v4f acc = gemm_phase<2>(cb, wl0, p0);
      lstm_epi_pack(acc, bias0, cs0, h0B + (size_t)sc*HB_SZ + hwoff, l15, gidx);
    }
    publish(&fh0r[bid], (unsigned)(t+1));

    // -- p1 = Whh1 @ h1[t-1] (fills the eh0 wait), then hop1 rendezvous
    v4f p1 = {0.f,0.f,0.f,0.f};
    {
      const char* hs = h1B + (size_t)sp*HB_SZ + aoffH;
      const char* cb[4] = { hs, hs+512, hs+1024, hs+1536 };
      p1 = gemm_phase<4>(cb, wl1r, p1);
      if (lead_h0) scan256_pub(fh0r, eh0, (unsigned)(t+1));
      else         wait_word(eh0, (unsigned)(t+1));
    }

    // -- L1 input part ONLY -> h1[t]; publish fh1 immediately (0.4us earlier)
    {
      const char* hs = h0B + (size_t)sc*HB_SZ + aoffH;
      const char* cb[4] = { hs, hs+512, hs+1024, hs+1536 };
      p1 = gemm_phase<4>(cb, wl1, p1);
      lstm_epi_pack(p1, bias1, cs1, h1B + (size_t)sc*HB_SZ + hwoff, l15, gidx);
    }
    publish(&fh1r[bid], (unsigned)(t+1));

    // -- hop2 + np0 filler: followers compute np0 then poll eh1 (window
    //    filled); lead_h1 relays FIRST, then computes np0 (its detection
    //    advantage over the relay path absorbs the np0 cost).
    {
      const char* hs = h0B + (size_t)sc*HB_SZ + aoffH;
      const char* cb[4] = { hs, hs+512, hs+1024, hs+1536 };
      v4f np0 = {0.f,0.f,0.f,0.f};
      if (lead_h1){
        scan256_pub(fh1r, eh1, (unsigned)(t+1));
        np0 = gemm_phase<4>(cb, wl0r, np0);
      } else {
        np0 = gemm_phase<4>(cb, wl0r, np0);
        wait_word(eh1, (unsigned)(t+1));
      }
      p0 = np0;
    }

    // -- FC (all blocks, 2 dims each): y[t] cols 2*bid..2*bid+1
    float yv[4];
    {
      const char* f1 = h1B + (size_t)sc*HB_SZ + aoffH;
      const char* cb[4] = { f1, f1+512, f1+1024, f1+1536 };
      v4f acc = {0.f,0.f,0.f,0.f};
      acc = gemm_phase<4>(cb, wlf, acc);
      char* ydst = yB + (size_t)sc*YB_SZ;
      #pragma unroll
      for (int r = 0; r < 4; r++){
        float v = fmaxf(acc[r] + biasf, 0.f);
        yv[r] = v;
        int b = rb + r;
        unsigned int uv = (unsigned int)__builtin_bit_cast(unsigned short, (_Float16)v);
        unsigned int o1 = (unsigned int)__shfl_xor((int)uv, 1);
        if (l15 == 0){
          unsigned int pr = uv | (o1 << 16);
          ast4(ydst + ((size_t)b*ODIM + bid*2)*2, pr);
        }
      }
    }
    publish(&fyr[bid], (unsigned)(t+1));

    // -- out stores AFTER the fy publish (consumed by nobody; drain later)
    #pragma unroll
    for (int r = 0; r < 4; r++){
      int b = rb + r;
      if (l15 < 2) out[((size_t)b*SEQL + t)*ODIM + bid*2 + l15] = yv[r];
    }
  }
}

extern "C" void kernel_launch(void* const* d_in, const int* in_sizes, int n_in,
                              void* d_out, int out_size, void* d_ws, size_t ws_size,
                              hipStream_t stream){
  (void)in_sizes; (void)n_in; (void)out_size;

  int D = 16;
  while (D > 2 && (size_t)D*(YB_SZ + 2*HB_SZ) + FLG_BYTES > ws_size) D >>= 1;
  if ((size_t)D*(YB_SZ + 2*HB_SZ) + FLG_BYTES > ws_size) return;

  char* ws  = (char*)d_ws;
  char* yB  = ws;
  char* h0B = yB + (size_t)D*YB_SZ;
  char* h1B = h0B + (size_t)D*HB_SZ;
  char* flg = h1B + (size_t)D*HB_SZ;

  const float* h0   = (const float*)d_in[1];
  const float* c0   = (const float*)d_in[2];
  const float* Wih0 = (const float*)d_in[3];
  const float* Whh0 = (const float*)d_in[4];
  const float* bih0 = (const float*)d_in[5];
  const float* bhh0 = (const float*)d_in[6];
  const float* Wih1 = (const float*)d_in[7];
  const float* Whh1 = (const float*)d_in[8];
  const float* bih1 = (const float*)d_in[9];
  const float* bhh1 = (const float*)d_in[10];
  const float* Wfc  = (const float*)d_in[11];
  const float* bfc  = (const float*)d_in[12];
  float* out = (float*)d_out;

  (void)hipMemsetAsync(flg, 0, FLG_BYTES, stream);
  hipLaunchKernelGGL(init_kernel, dim3(256), dim3(256), 0, stream,
                     h0,
                     (_Float16*)(h0B + (size_t)(D-1)*HB_SZ),
                     (_Float16*)(h1B + (size_t)(D-1)*HB_SZ),
                     (_Float16*)(yB  + (size_t)(D-1)*YB_SZ));

  (void)hipFuncSetAttribute((const void*)decoder_kernel,
                            hipFuncAttributeMaxDynamicSharedMemorySize, SMEM_BYTES);
  hipLaunchKernelGGL(decoder_kernel, dim3(NBLK), dim3(NTHR), SMEM_BYTES, stream,
                     Wih0, Whh0, bih0, bhh0, Wih1, Whh1, bih1, bhh1,
                     Wfc, bfc, c0, out, yB, h0B, h1B, flg, D - 1);
}

// Round 16
// 4917.575 us; speedup vs baseline: 1.9959x; 1.1855x over previous
//
#include <hip/hip_runtime.h>
#include <stdint.h>

// ---------------------------------------------------------------------------
// Persistent-RNN 2-layer LSTM decoder (B=64,H=1024,OUT=512,SEQ=256), MI355X.
// R16 = R12 byte-identical revert (best measured: 4.92 ms).
// Structure: symmetric 3-hop pipeline —
//  * 256 WGs (1/CU) x 256 thr; weights fp16 in LDS (loaded once).
//  * rotating write-once activation buffers (depth D): normal cached loads
//    coherent with NO per-step invalidation; buffer_inv once per D steps.
//  * store-only per-wave flags + leader-relayed epochs (8 leaders/hop,
//    disjoint octets); no atomic RMW (R5), no direct 256-scans by all (R14).
//  * FC distributed 2 dims/block (hop symmetry, R12's win over R9/R11).
//  * fused dual gemm (L1-input + next-step L0-recurrent, shared A-loads) —
//    splitting it regresses (R13, R15).
// ---------------------------------------------------------------------------

#define NBLK 256
#define NTHR 256
#define HDIM 1024
#define ODIM 512
#define BDIM 64
#define SEQL 256

typedef _Float16 v8h __attribute__((ext_vector_type(8)));
typedef float    v4f __attribute__((ext_vector_type(4)));

// LDS: per k-slice, 64 lanes x 16B contiguous = 1024B (conflict-free b128)
#define WL0_NS 48
#define WL1_NS 64
#define WFC_NS 32
#define WL0_OFF 0
#define WL1_OFF (WL0_NS*1024)
#define WFC_OFF (WL1_OFF + WL1_NS*1024)
#define SMEM_BYTES (WFC_OFF + WFC_NS*1024)   // 147456 B

#define YB_SZ  (BDIM*ODIM*2)            // 64 KB per slot
#define HB_SZ  (BDIM*HDIM*2)            // 128 KB per slot

// flags: fh0[4][256], fh1[4][256], fy[4][256] packed 4B
// epochs: eh0/eh1/ey [(wv,f)] one word each, 64B stride.
#define FH0_REL 0
#define FH1_REL (4*256*4)
#define FY_REL  (FH1_REL + 4*256*4)
#define EH0_REL (FY_REL + 4*256*4)
#define EH1_REL (EH0_REL + 4*8*64)
#define EY_REL  (EH1_REL + 4*8*64)
#define FLG_BYTES (EY_REL + 4*8*64)

__device__ __forceinline__ float fsig(float x)   { return 1.0f / (1.0f + __expf(-x)); }
__device__ __forceinline__ float ftanhf(float x) { return 1.0f - 2.0f / (__expf(2.0f*x) + 1.0f); }

__device__ __forceinline__ unsigned long long ald8(const void* p){
  return __hip_atomic_load((const unsigned long long*)p, __ATOMIC_RELAXED, __HIP_MEMORY_SCOPE_AGENT);
}
__device__ __forceinline__ unsigned int ald4(const void* p){
  return __hip_atomic_load((const unsigned int*)p, __ATOMIC_RELAXED, __HIP_MEMORY_SCOPE_AGENT);
}
__device__ __forceinline__ void ast4(void* p, unsigned int v){
  __hip_atomic_store((unsigned int*)p, v, __ATOMIC_RELAXED, __HIP_MEMORY_SCOPE_AGENT);
}

// wrap-acquire: once per D steps — drop last-epoch clean L2 lines.
__device__ __forceinline__ void wrap_inv(){
  asm volatile("s_waitcnt vmcnt(0)\n\tbuffer_inv sc1" ::: "memory");
}

// follower: poll one epoch word with light sleep
__device__ __forceinline__ void wait_word(const unsigned int* w, unsigned int tag){
  while (ald4(w) < tag) __builtin_amdgcn_s_sleep(1);
  asm volatile("" ::: "memory");
}

// leader: scan full 256-flag row (4 flags/lane), then store epoch word
__device__ __forceinline__ void scan256_pub(const unsigned int* rowf, unsigned int* ew,
                                            unsigned int tag){
  const char* p = (const char*)(rowf + (threadIdx.x & 63)*4);
  while (true){
    unsigned long long a = ald8(p);
    unsigned long long b = ald8(p+8);
    unsigned int m0 = (unsigned int)a, m1 = (unsigned int)(a >> 32);
    unsigned int m2 = (unsigned int)b, m3 = (unsigned int)(b >> 32);
    unsigned int m = min(min(m0, m1), min(m2, m3));
    if (__all(m >= tag)) break;
    __builtin_amdgcn_s_sleep(1);
  }
  if ((threadIdx.x & 63) == 0) ast4(ew, tag);
  asm volatile("" ::: "memory");
}

// wave publish: drain this wave's vmem (reads+writes), store tag (1 writer).
__device__ __forceinline__ void publish(unsigned int* flag, unsigned int tag){
  asm volatile("s_waitcnt vmcnt(0)" ::: "memory");
  if ((threadIdx.x & 63) == 0) ast4(flag, tag);
}

// K-loop: NC chunks of 256 K-cols (8 MFMAs each); A via normal cached loads.
template<int NC>
__device__ __forceinline__ v4f gemm_phase(const char* const cb[], const char* wl, v4f acc){
  v8h A[4][8];
  constexpr int PF = (NC < 3) ? NC : 3;
  #pragma unroll
  for (int p = 0; p < PF; p++){
    #pragma unroll
    for (int j = 0; j < 8; j++) A[p][j] = *(const v8h*)(cb[p] + (size_t)j*64);
  }
  #pragma unroll
  for (int c = 0; c < NC; c++){
    const int cur = c & 3, nx = (c + 3) & 3;
    if (c + 3 < NC){
      #pragma unroll
      for (int j = 0; j < 8; j++) A[nx][j] = *(const v8h*)(cb[c+3] + (size_t)j*64);
    }
    #pragma unroll
    for (int j = 0; j < 8; j++){
      v8h B = *(const v8h*)(wl + (size_t)(c*8 + j)*1024);
      acc = __builtin_amdgcn_mfma_f32_16x16x32_f16(A[cur][j], B, acc, 0, 0, 0);
    }
  }
  return acc;
}

// Same A-stream feeding two B matrices (L1 input-part + next-step L0 recurrent).
__device__ __forceinline__ void gemm_dual4(const char* const cb[], const char* wlA,
                                           const char* wlB, v4f& accA, v4f& accB){
  v8h A[4][8];
  #pragma unroll
  for (int p = 0; p < 3; p++){
    #pragma unroll
    for (int j = 0; j < 8; j++) A[p][j] = *(const v8h*)(cb[p] + (size_t)j*64);
  }
  #pragma unroll
  for (int c = 0; c < 4; c++){
    const int cur = c & 3, nx = (c + 3) & 3;
    if (c + 3 < 4){
      #pragma unroll
      for (int j = 0; j < 8; j++) A[nx][j] = *(const v8h*)(cb[c+3] + (size_t)j*64);
    }
    #pragma unroll
    for (int j = 0; j < 8; j++){
      v8h BA = *(const v8h*)(wlA + (size_t)(c*8 + j)*1024);
      accA = __builtin_amdgcn_mfma_f32_16x16x32_f16(A[cur][j], BA, accA, 0, 0, 0);
      v8h BB = *(const v8h*)(wlB + (size_t)(c*8 + j)*1024);
      accB = __builtin_amdgcn_mfma_f32_16x16x32_f16(A[cur][j], BB, accB, 0, 0, 0);
    }
  }
}

// LSTM epilogue: gate gather via xor1/2/3; h packed 4 units -> one 8B sc1 store.
__device__ __forceinline__ void lstm_epi_pack(v4f acc, float bias, float* cs,
                                              char* hbase, int l15, int gidx){
  #pragma unroll
  for (int r = 0; r < 4; r++){
    float v  = acc[r] + bias;
    float x1 = __shfl_xor(v, 1);
    float x2 = __shfl_xor(v, 2);
    float x3 = __shfl_xor(v, 3);
    float vi = (gidx==0)?v :(gidx==1)?x1:(gidx==2)?x2:x3;
    float vf = (gidx==1)?v :(gidx==0)?x1:(gidx==3)?x2:x3;
    float vg = (gidx==2)?v :(gidx==3)?x1:(gidx==0)?x2:x3;
    float vo = (gidx==3)?v :(gidx==2)?x1:(gidx==1)?x2:x3;
    float ii = fsig(vi), ff = fsig(vf), gg = ftanhf(vg), oo = fsig(vo);
    float cn = ff*cs[r] + ii*gg;
    cs[r] = cn;
    float hn = oo * ftanhf(cn);
    unsigned int uv = (unsigned int)__builtin_bit_cast(unsigned short, (_Float16)hn);
    unsigned int o4 = (unsigned int)__shfl_xor((int)uv, 4);
    unsigned int pr = uv | (o4 << 16);
    unsigned int o8 = (unsigned int)__shfl_xor((int)pr, 8);
    if (l15 == 0){
      unsigned long long full = (unsigned long long)pr | ((unsigned long long)o8 << 32);
      __hip_atomic_store((unsigned long long*)(hbase + (size_t)r*(HDIM*2)), full,
                         __ATOMIC_RELAXED, __HIP_MEMORY_SCOPE_AGENT);
    }
  }
}

__global__ void init_kernel(const float* __restrict__ h0,
                            _Float16* __restrict__ h0bi, _Float16* __restrict__ h1bi,
                            _Float16* __restrict__ ybi){
  int i = blockIdx.x*256 + threadIdx.x;
  if (i < BDIM*HDIM){
    h0bi[i] = (_Float16)h0[i];
    h1bi[i] = (_Float16)h0[BDIM*HDIM + i];
  }
  if (i < BDIM*ODIM) ybi[i] = (_Float16)(-2.0f); // SOS
}

__launch_bounds__(NTHR, 1)
__global__ void decoder_kernel(
    const float* __restrict__ Wih0, const float* __restrict__ Whh0,
    const float* __restrict__ bih0, const float* __restrict__ bhh0,
    const float* __restrict__ Wih1, const float* __restrict__ Whh1,
    const float* __restrict__ bih1, const float* __restrict__ bhh1,
    const float* __restrict__ Wfc,  const float* __restrict__ bfc,
    const float* __restrict__ c0in, float* __restrict__ out,
    char* __restrict__ yB, char* __restrict__ h0B, char* __restrict__ h1B,
    char* __restrict__ flg, int dmask)
{
  extern __shared__ char smem[];
  const int bid = blockIdx.x;
  const int tid = threadIdx.x;
  const int wv  = tid >> 6;
  const int ln  = tid & 63;
  const int l15 = ln & 15;
  const int lq  = ln >> 4;
  const int u0  = bid * 4;
  const int f   = bid & 7;
  const int lead_h0 = (bid < 8);
  const int lead_h1 = (bid >= 8  && bid < 16);
  const int lead_y  = (bid >= 16 && bid < 24);

  unsigned int* fh0r = (unsigned int*)(flg + FH0_REL) + wv*256;
  unsigned int* fh1r = (unsigned int*)(flg + FH1_REL) + wv*256;
  unsigned int* fyr  = (unsigned int*)(flg + FY_REL)  + wv*256;
  unsigned int* eh0  = (unsigned int*)(flg + EH0_REL + (wv*8 + f)*64);
  unsigned int* eh1  = (unsigned int*)(flg + EH1_REL + (wv*8 + f)*64);
  unsigned int* ey   = (unsigned int*)(flg + EY_REL  + (wv*8 + f)*64);

  // ---- one-time: weights fp32->fp16 into LDS, exact fragment order ----
  for (int slot = tid; slot < WL0_NS*64; slot += NTHR){
    int s = slot >> 6, l = slot & 63;
    int r16 = l & 15, q = l >> 4;
    int grow = (r16 & 3)*HDIM + u0 + (r16 >> 2);
    int kb = s*32 + q*8;
    const float* src; int k0;
    if (kb < ODIM){ src = Wih0 + (size_t)grow*ODIM; k0 = kb; }
    else          { src = Whh0 + (size_t)grow*HDIM; k0 = kb - ODIM; }
    v8h hv;
    #pragma unroll
    for (int j = 0; j < 8; j++) hv[j] = (_Float16)src[k0 + j];
    *(v8h*)(smem + WL0_OFF + s*1024 + l*16) = hv;
  }
  for (int slot = tid; slot < WL1_NS*64; slot += NTHR){
    int s = slot >> 6, l = slot & 63;
    int r16 = l & 15, q = l >> 4;
    int grow = (r16 & 3)*HDIM + u0 + (r16 >> 2);
    int kb = s*32 + q*8;
    const float* src; int k0;
    if (kb < HDIM){ src = Wih1 + (size_t)grow*HDIM; k0 = kb; }
    else          { src = Whh1 + (size_t)grow*HDIM; k0 = kb - HDIM; }
    v8h hv;
    #pragma unroll
    for (int j = 0; j < 8; j++) hv[j] = (_Float16)src[k0 + j];
    *(v8h*)(smem + WL1_OFF + s*1024 + l*16) = hv;
  }
  // FC tile: rows 0..1 = dims 2*bid, 2*bid+1; rows 2..15 zero (all blocks)
  for (int slot = tid; slot < WFC_NS*64; slot += NTHR){
    int s = slot >> 6, l = slot & 63;
    int r16 = l & 15, q = l >> 4;
    int k0 = s*32 + q*8;
    v8h hv;
    if (r16 < 2){
      const float* src = Wfc + (size_t)(bid*2 + r16)*HDIM;
      #pragma unroll
      for (int j = 0; j < 8; j++) hv[j] = (_Float16)src[k0 + j];
    } else {
      #pragma unroll
      for (int j = 0; j < 8; j++) hv[j] = (_Float16)0.0f;
    }
    *(v8h*)(smem + WFC_OFF + s*1024 + l*16) = hv;
  }
  __syncthreads();   // LDS weights ready (only barrier in the kernel)

  // ---- per-lane constants ----
  const int gidx = l15 & 3;
  const int unit = u0 + (l15 >> 2);
  const int growL = gidx*HDIM + unit;
  const float bias0 = bih0[growL] + bhh0[growL];
  const float bias1 = bih1[growL] + bhh1[growL];
  const float biasf = (l15 < 2) ? bfc[bid*2 + l15] : 0.f;

  const int rb = wv*16 + lq*4;
  float cs0[4], cs1[4];
  #pragma unroll
  for (int r = 0; r < 4; r++){
    int b = rb + r;
    cs0[r] = c0in[(size_t)(0*BDIM + b)*HDIM + unit];
    cs1[r] = c0in[(size_t)(1*BDIM + b)*HDIM + unit];
  }

  const int row = wv*16 + l15;
  const size_t aoffY = (size_t)row*ODIM*2 + (size_t)lq*16;
  const size_t aoffH = (size_t)row*HDIM*2 + (size_t)lq*16;
  const size_t hwoff = ((size_t)rb*HDIM + u0)*2;
  const char* wl0 = smem + WL0_OFF + ln*16;
  const char* wl1 = smem + WL1_OFF + ln*16;
  const char* wlf = smem + WFC_OFF + ln*16;
  const char* wl0r = wl0 + 16*1024;   // Whh0 slices
  const char* wl1r = wl1 + 32*1024;   // Whh1 slices

  // prologue: p0 = Whh0 @ h0_init
  v4f p0 = {0.f,0.f,0.f,0.f};
  {
    const char* hi = h0B + (size_t)dmask*HB_SZ + aoffH;
    const char* cb[4] = { hi, hi+512, hi+1024, hi+1536 };
    p0 = gemm_phase<4>(cb, wl0r, p0);
  }

  for (int t = 0; t < SEQL; t++){
    const int sp = (t - 1) & dmask;
    const int sc = t & dmask;

    if ((t & dmask) == 0) wrap_inv();  // once per rotation epoch

    // -- hop3 tail: y[t-1] ready? (leaders 16..23 scan fy; others poll ey)
    if (t > 0){
      if (lead_y) scan256_pub(fyr, ey, (unsigned)t);
      else        wait_word(ey, (unsigned)t);
    }

    // -- L0 input part (K=512) + recurrent partial -> h0[t]
    {
      const char* ysrc = yB + (size_t)sp*YB_SZ + aoffY;
      const char* cb[2] = { ysrc, ysrc+512 };
      v4f acc = gemm_phase<2>(cb, wl0, p0);
      lstm_epi_pack(acc, bias0, cs0, h0B + (size_t)sc*HB_SZ + hwoff, l15, gidx);
    }
    publish(&fh0r[bid], (unsigned)(t+1));

    // -- p1 = Whh1 @ h1[t-1] (fills the eh0 wait), then hop1 rendezvous
    v4f p1 = {0.f,0.f,0.f,0.f};
    {
      const char* hs = h1B + (size_t)sp*HB_SZ + aoffH;
      const char* cb[4] = { hs, hs+512, hs+1024, hs+1536 };
      p1 = gemm_phase<4>(cb, wl1r, p1);
      if (lead_h0) scan256_pub(fh0r, eh0, (unsigned)(t+1));
      else         wait_word(eh0, (unsigned)(t+1));
    }

    // -- L1 input part + fused next-step L0 recurrent (shared A) -> h1[t]
    {
      const char* hs = h0B + (size_t)sc*HB_SZ + aoffH;
      const char* cb[4] = { hs, hs+512, hs+1024, hs+1536 };
      v4f np0 = {0.f,0.f,0.f,0.f};
      gemm_dual4(cb, wl1, wl0r, p1, np0);
      lstm_epi_pack(p1, bias1, cs1, h1B + (size_t)sc*HB_SZ + hwoff, l15, gidx);
      p0 = np0;
    }
    publish(&fh1r[bid], (unsigned)(t+1));

    // -- hop2: fh1 rendezvous (leaders 8..15 scan; others poll eh1)
    if (lead_h1) scan256_pub(fh1r, eh1, (unsigned)(t+1));
    else         wait_word(eh1, (unsigned)(t+1));

    // -- FC (all blocks, 2 dims each): y[t] cols 2*bid..2*bid+1
    {
      const char* f1 = h1B + (size_t)sc*HB_SZ + aoffH;
      const char* cb[4] = { f1, f1+512, f1+1024, f1+1536 };
      v4f acc = {0.f,0.f,0.f,0.f};
      acc = gemm_phase<4>(cb, wlf, acc);
      char* ydst = yB + (size_t)sc*YB_SZ;
      #pragma unroll
      for (int r = 0; r < 4; r++){
        float v = fmaxf(acc[r] + biasf, 0.f);
        int b = rb + r;
        // y fp16 pair store (dims 2*bid, 2*bid+1) by l15==0 lanes
        unsigned int uv = (unsigned int)__builtin_bit_cast(unsigned short, (_Float16)v);
        unsigned int o1 = (unsigned int)__shfl_xor((int)uv, 1);
        if (l15 == 0){
          unsigned int pr = uv | (o1 << 16);
          ast4(ydst + ((size_t)b*ODIM + bid*2)*2, pr);
        }
        // out float store (2 lanes per row)
        if (l15 < 2) out[((size_t)b*SEQL + t)*ODIM + bid*2 + l15] = v;
      }
    }
    publish(&fyr[bid], (unsigned)(t+1));
  }
}

extern "C" void kernel_launch(void* const* d_in, const int* in_sizes, int n_in,
                              void* d_out, int out_size, void* d_ws, size_t ws_size,
                              hipStream_t stream){
  (void)in_sizes; (void)n_in; (void)out_size;

  int D = 16;
  while (D > 2 && (size_t)D*(YB_SZ + 2*HB_SZ) + FLG_BYTES > ws_size) D >>= 1;
  if ((size_t)D*(YB_SZ + 2*HB_SZ) + FLG_BYTES > ws_size) return;

  char* ws  = (char*)d_ws;
  char* yB  = ws;
  char* h0B = yB + (size_t)D*YB_SZ;
  char* h1B = h0B + (size_t)D*HB_SZ;
  char* flg = h1B + (size_t)D*HB_SZ;

  const float* h0   = (const float*)d_in[1];
  const float* c0   = (const float*)d_in[2];
  const float* Wih0 = (const float*)d_in[3];
  const float* Whh0 = (const float*)d_in[4];
  const float* bih0 = (const float*)d_in[5];
  const float* bhh0 = (const float*)d_in[6];
  const float* Wih1 = (const float*)d_in[7];
  const float* Whh1 = (const float*)d_in[8];
  const float* bih1 = (const float*)d_in[9];
  const float* bhh1 = (const float*)d_in[10];
  const float* Wfc  = (const float*)d_in[11];
  const float* bfc  = (const float*)d_in[12];
  float* out = (float*)d_out;

  (void)hipMemsetAsync(flg, 0, FLG_BYTES, stream);
  hipLaunchKernelGGL(init_kernel, dim3(256), dim3(256), 0, stream,
                     h0,
                     (_Float16*)(h0B + (size_t)(D-1)*HB_SZ),
                     (_Float16*)(h1B + (size_t)(D-1)*HB_SZ),
                     (_Float16*)(yB  + (size_t)(D-1)*YB_SZ));

  (void)hipFuncSetAttribute((const void*)decoder_kernel,
                            hipFuncAttributeMaxDynamicSharedMemorySize, SMEM_BYTES);
  hipLaunchKernelGGL(decoder_kernel, dim3(NBLK), dim3(NTHR), SMEM_BYTES, stream,
                     Wih0, Whh0, bih0, bhh0, Wih1, Whh1, bih1, bhh1,
                     Wfc, bfc, c0, out, yB, h0B, h1B, flg, D - 1);
}

// Round 17
// 4889.120 us; speedup vs baseline: 2.0075x; 1.0058x over previous
//
#include <hip/hip_runtime.h>
#include <stdint.h>

// ---------------------------------------------------------------------------
// Persistent-RNN 2-layer LSTM decoder (B=64,H=1024,OUT=512,SEQ=256), MI355X.
// R17 = R12/R16 + ONE isolated change: out[] stores moved AFTER the fy
// publish. out is consumed by nobody in-kernel; its scattered 4B stores
// (write-allocate partial lines) previously sat on the fy publish's
// vmcnt(0) drain — hop 3's critical edge. Now they retire under the next
// step's L0 gemm. Everything else byte-identical to R16 (4.92 ms anchor):
//  * rotating write-once activation buffers (depth D), cached reads,
//    buffer_inv once per D steps.
//  * store-only per-wave flags + leader-relayed epochs (disjoint octets).
//  * FC distributed 2 dims/block (hop symmetry).
//  * fused dual gemm (splitting regresses: R13, R15).
// ---------------------------------------------------------------------------

#define NBLK 256
#define NTHR 256
#define HDIM 1024
#define ODIM 512
#define BDIM 64
#define SEQL 256

typedef _Float16 v8h __attribute__((ext_vector_type(8)));
typedef float    v4f __attribute__((ext_vector_type(4)));

// LDS: per k-slice, 64 lanes x 16B contiguous = 1024B (conflict-free b128)
#define WL0_NS 48
#define WL1_NS 64
#define WFC_NS 32
#define WL0_OFF 0
#define WL1_OFF (WL0_NS*1024)
#define WFC_OFF (WL1_OFF + WL1_NS*1024)
#define SMEM_BYTES (WFC_OFF + WFC_NS*1024)   // 147456 B

#define YB_SZ  (BDIM*ODIM*2)            // 64 KB per slot
#define HB_SZ  (BDIM*HDIM*2)            // 128 KB per slot

// flags: fh0[4][256], fh1[4][256], fy[4][256] packed 4B
// epochs: eh0/eh1/ey [(wv,f)] one word each, 64B stride.
#define FH0_REL 0
#define FH1_REL (4*256*4)
#define FY_REL  (FH1_REL + 4*256*4)
#define EH0_REL (FY_REL + 4*256*4)
#define EH1_REL (EH0_REL + 4*8*64)
#define EY_REL  (EH1_REL + 4*8*64)
#define FLG_BYTES (EY_REL + 4*8*64)

__device__ __forceinline__ float fsig(float x)   { return 1.0f / (1.0f + __expf(-x)); }
__device__ __forceinline__ float ftanhf(float x) { return 1.0f - 2.0f / (__expf(2.0f*x) + 1.0f); }

__device__ __forceinline__ unsigned long long ald8(const void* p){
  return __hip_atomic_load((const unsigned long long*)p, __ATOMIC_RELAXED, __HIP_MEMORY_SCOPE_AGENT);
}
__device__ __forceinline__ unsigned int ald4(const void* p){
  return __hip_atomic_load((const unsigned int*)p, __ATOMIC_RELAXED, __HIP_MEMORY_SCOPE_AGENT);
}
__device__ __forceinline__ void ast4(void* p, unsigned int v){
  __hip_atomic_store((unsigned int*)p, v, __ATOMIC_RELAXED, __HIP_MEMORY_SCOPE_AGENT);
}

// wrap-acquire: once per D steps — drop last-epoch clean L2 lines.
__device__ __forceinline__ void wrap_inv(){
  asm volatile("s_waitcnt vmcnt(0)\n\tbuffer_inv sc1" ::: "memory");
}

// follower: poll one epoch word with light sleep
__device__ __forceinline__ void wait_word(const unsigned int* w, unsigned int tag){
  while (ald4(w) < tag) __builtin_amdgcn_s_sleep(1);
  asm volatile("" ::: "memory");
}

// leader: scan full 256-flag row (4 flags/lane), then store epoch word
__device__ __forceinline__ void scan256_pub(const unsigned int* rowf, unsigned int* ew,
                                            unsigned int tag){
  const char* p = (const char*)(rowf + (threadIdx.x & 63)*4);
  while (true){
    unsigned long long a = ald8(p);
    unsigned long long b = ald8(p+8);
    unsigned int m0 = (unsigned int)a, m1 = (unsigned int)(a >> 32);
    unsigned int m2 = (unsigned int)b, m3 = (unsigned int)(b >> 32);
    unsigned int m = min(min(m0, m1), min(m2, m3));
    if (__all(m >= tag)) break;
    __builtin_amdgcn_s_sleep(1);
  }
  if ((threadIdx.x & 63) == 0) ast4(ew, tag);
  asm volatile("" ::: "memory");
}

// wave publish: drain this wave's vmem (reads+writes), store tag (1 writer).
__device__ __forceinline__ void publish(unsigned int* flag, unsigned int tag){
  asm volatile("s_waitcnt vmcnt(0)" ::: "memory");
  if ((threadIdx.x & 63) == 0) ast4(flag, tag);
}

// K-loop: NC chunks of 256 K-cols (8 MFMAs each); A via normal cached loads.
template<int NC>
__device__ __forceinline__ v4f gemm_phase(const char* const cb[], const char* wl, v4f acc){
  v8h A[4][8];
  constexpr int PF = (NC < 3) ? NC : 3;
  #pragma unroll
  for (int p = 0; p < PF; p++){
    #pragma unroll
    for (int j = 0; j < 8; j++) A[p][j] = *(const v8h*)(cb[p] + (size_t)j*64);
  }
  #pragma unroll
  for (int c = 0; c < NC; c++){
    const int cur = c & 3, nx = (c + 3) & 3;
    if (c + 3 < NC){
      #pragma unroll
      for (int j = 0; j < 8; j++) A[nx][j] = *(const v8h*)(cb[c+3] + (size_t)j*64);
    }
    #pragma unroll
    for (int j = 0; j < 8; j++){
      v8h B = *(const v8h*)(wl + (size_t)(c*8 + j)*1024);
      acc = __builtin_amdgcn_mfma_f32_16x16x32_f16(A[cur][j], B, acc, 0, 0, 0);
    }
  }
  return acc;
}

// Same A-stream feeding two B matrices (L1 input-part + next-step L0 recurrent).
__device__ __forceinline__ void gemm_dual4(const char* const cb[], const char* wlA,
                                           const char* wlB, v4f& accA, v4f& accB){
  v8h A[4][8];
  #pragma unroll
  for (int p = 0; p < 3; p++){
    #pragma unroll
    for (int j = 0; j < 8; j++) A[p][j] = *(const v8h*)(cb[p] + (size_t)j*64);
  }
  #pragma unroll
  for (int c = 0; c < 4; c++){
    const int cur = c & 3, nx = (c + 3) & 3;
    if (c + 3 < 4){
      #pragma unroll
      for (int j = 0; j < 8; j++) A[nx][j] = *(const v8h*)(cb[c+3] + (size_t)j*64);
    }
    #pragma unroll
    for (int j = 0; j < 8; j++){
      v8h BA = *(const v8h*)(wlA + (size_t)(c*8 + j)*1024);
      accA = __builtin_amdgcn_mfma_f32_16x16x32_f16(A[cur][j], BA, accA, 0, 0, 0);
      v8h BB = *(const v8h*)(wlB + (size_t)(c*8 + j)*1024);
      accB = __builtin_amdgcn_mfma_f32_16x16x32_f16(A[cur][j], BB, accB, 0, 0, 0);
    }
  }
}

// LSTM epilogue: gate gather via xor1/2/3; h packed 4 units -> one 8B sc1 store.
__device__ __forceinline__ void lstm_epi_pack(v4f acc, float bias, float* cs,
                                              char* hbase, int l15, int gidx){
  #pragma unroll
  for (int r = 0; r < 4; r++){
    float v  = acc[r] + bias;
    float x1 = __shfl_xor(v, 1);
    float x2 = __shfl_xor(v, 2);
    float x3 = __shfl_xor(v, 3);
    float vi = (gidx==0)?v :(gidx==1)?x1:(gidx==2)?x2:x3;
    float vf = (gidx==1)?v :(gidx==0)?x1:(gidx==3)?x2:x3;
    float vg = (gidx==2)?v :(gidx==3)?x1:(gidx==0)?x2:x3;
    float vo = (gidx==3)?v :(gidx==2)?x1:(gidx==1)?x2:x3;
    float ii = fsig(vi), ff = fsig(vf), gg = ftanhf(vg), oo = fsig(vo);
    float cn = ff*cs[r] + ii*gg;
    cs[r] = cn;
    float hn = oo * ftanhf(cn);
    unsigned int uv = (unsigned int)__builtin_bit_cast(unsigned short, (_Float16)hn);
    unsigned int o4 = (unsigned int)__shfl_xor((int)uv, 4);
    unsigned int pr = uv | (o4 << 16);
    unsigned int o8 = (unsigned int)__shfl_xor((int)pr, 8);
    if (l15 == 0){
      unsigned long long full = (unsigned long long)pr | ((unsigned long long)o8 << 32);
      __hip_atomic_store((unsigned long long*)(hbase + (size_t)r*(HDIM*2)), full,
                         __ATOMIC_RELAXED, __HIP_MEMORY_SCOPE_AGENT);
    }
  }
}

__global__ void init_kernel(const float* __restrict__ h0,
                            _Float16* __restrict__ h0bi, _Float16* __restrict__ h1bi,
                            _Float16* __restrict__ ybi){
  int i = blockIdx.x*256 + threadIdx.x;
  if (i < BDIM*HDIM){
    h0bi[i] = (_Float16)h0[i];
    h1bi[i] = (_Float16)h0[BDIM*HDIM + i];
  }
  if (i < BDIM*ODIM) ybi[i] = (_Float16)(-2.0f); // SOS
}

__launch_bounds__(NTHR, 1)
__global__ void decoder_kernel(
    const float* __restrict__ Wih0, const float* __restrict__ Whh0,
    const float* __restrict__ bih0, const float* __restrict__ bhh0,
    const float* __restrict__ Wih1, const float* __restrict__ Whh1,
    const float* __restrict__ bih1, const float* __restrict__ bhh1,
    const float* __restrict__ Wfc,  const float* __restrict__ bfc,
    const float* __restrict__ c0in, float* __restrict__ out,
    char* __restrict__ yB, char* __restrict__ h0B, char* __restrict__ h1B,
    char* __restrict__ flg, int dmask)
{
  extern __shared__ char smem[];
  const int bid = blockIdx.x;
  const int tid = threadIdx.x;
  const int wv  = tid >> 6;
  const int ln  = tid & 63;
  const int l15 = ln & 15;
  const int lq  = ln >> 4;
  const int u0  = bid * 4;
  const int f   = bid & 7;
  const int lead_h0 = (bid < 8);
  const int lead_h1 = (bid >= 8  && bid < 16);
  const int lead_y  = (bid >= 16 && bid < 24);

  unsigned int* fh0r = (unsigned int*)(flg + FH0_REL) + wv*256;
  unsigned int* fh1r = (unsigned int*)(flg + FH1_REL) + wv*256;
  unsigned int* fyr  = (unsigned int*)(flg + FY_REL)  + wv*256;
  unsigned int* eh0  = (unsigned int*)(flg + EH0_REL + (wv*8 + f)*64);
  unsigned int* eh1  = (unsigned int*)(flg + EH1_REL + (wv*8 + f)*64);
  unsigned int* ey   = (unsigned int*)(flg + EY_REL  + (wv*8 + f)*64);

  // ---- one-time: weights fp32->fp16 into LDS, exact fragment order ----
  for (int slot = tid; slot < WL0_NS*64; slot += NTHR){
    int s = slot >> 6, l = slot & 63;
    int r16 = l & 15, q = l >> 4;
    int grow = (r16 & 3)*HDIM + u0 + (r16 >> 2);
    int kb = s*32 + q*8;
    const float* src; int k0;
    if (kb < ODIM){ src = Wih0 + (size_t)grow*ODIM; k0 = kb; }
    else          { src = Whh0 + (size_t)grow*HDIM; k0 = kb - ODIM; }
    v8h hv;
    #pragma unroll
    for (int j = 0; j < 8; j++) hv[j] = (_Float16)src[k0 + j];
    *(v8h*)(smem + WL0_OFF + s*1024 + l*16) = hv;
  }
  for (int slot = tid; slot < WL1_NS*64; slot += NTHR){
    int s = slot >> 6, l = slot & 63;
    int r16 = l & 15, q = l >> 4;
    int grow = (r16 & 3)*HDIM + u0 + (r16 >> 2);
    int kb = s*32 + q*8;
    const float* src; int k0;
    if (kb < HDIM){ src = Wih1 + (size_t)grow*HDIM; k0 = kb; }
    else          { src = Whh1 + (size_t)grow*HDIM; k0 = kb - HDIM; }
    v8h hv;
    #pragma unroll
    for (int j = 0; j < 8; j++) hv[j] = (_Float16)src[k0 + j];
    *(v8h*)(smem + WL1_OFF + s*1024 + l*16) = hv;
  }
  // FC tile: rows 0..1 = dims 2*bid, 2*bid+1; rows 2..15 zero (all blocks)
  for (int slot = tid; slot < WFC_NS*64; slot += NTHR){
    int s = slot >> 6, l = slot & 63;
    int r16 = l & 15, q = l >> 4;
    int k0 = s*32 + q*8;
    v8h hv;
    if (r16 < 2){
      const float* src = Wfc + (size_t)(bid*2 + r16)*HDIM;
      #pragma unroll
      for (int j = 0; j < 8; j++) hv[j] = (_Float16)src[k0 + j];
    } else {
      #pragma unroll
      for (int j = 0; j < 8; j++) hv[j] = (_Float16)0.0f;
    }
    *(v8h*)(smem + WFC_OFF + s*1024 + l*16) = hv;
  }
  __syncthreads();   // LDS weights ready (only barrier in the kernel)

  // ---- per-lane constants ----
  const int gidx = l15 & 3;
  const int unit = u0 + (l15 >> 2);
  const int growL = gidx*HDIM + unit;
  const float bias0 = bih0[growL] + bhh0[growL];
  const float bias1 = bih1[growL] + bhh1[growL];
  const float biasf = (l15 < 2) ? bfc[bid*2 + l15] : 0.f;

  const int rb = wv*16 + lq*4;
  float cs0[4], cs1[4];
  #pragma unroll
  for (int r = 0; r < 4; r++){
    int b = rb + r;
    cs0[r] = c0in[(size_t)(0*BDIM + b)*HDIM + unit];
    cs1[r] = c0in[(size_t)(1*BDIM + b)*HDIM + unit];
  }

  const int row = wv*16 + l15;
  const size_t aoffY = (size_t)row*ODIM*2 + (size_t)lq*16;
  const size_t aoffH = (size_t)row*HDIM*2 + (size_t)lq*16;
  const size_t hwoff = ((size_t)rb*HDIM + u0)*2;
  const char* wl0 = smem + WL0_OFF + ln*16;
  const char* wl1 = smem + WL1_OFF + ln*16;
  const char* wlf = smem + WFC_OFF + ln*16;
  const char* wl0r = wl0 + 16*1024;   // Whh0 slices
  const char* wl1r = wl1 + 32*1024;   // Whh1 slices

  // prologue: p0 = Whh0 @ h0_init
  v4f p0 = {0.f,0.f,0.f,0.f};
  {
    const char* hi = h0B + (size_t)dmask*HB_SZ + aoffH;
    const char* cb[4] = { hi, hi+512, hi+1024, hi+1536 };
    p0 = gemm_phase<4>(cb, wl0r, p0);
  }

  for (int t = 0; t < SEQL; t++){
    const int sp = (t - 1) & dmask;
    const int sc = t & dmask;

    if ((t & dmask) == 0) wrap_inv();  // once per rotation epoch

    // -- hop3 tail: y[t-1] ready? (leaders 16..23 scan fy; others poll ey)
    if (t > 0){
      if (lead_y) scan256_pub(fyr, ey, (unsigned)t);
      else        wait_word(ey, (unsigned)t);
    }

    // -- L0 input part (K=512) + recurrent partial -> h0[t]
    {
      const char* ysrc = yB + (size_t)sp*YB_SZ + aoffY;
      const char* cb[2] = { ysrc, ysrc+512 };
      v4f acc = gemm_phase<2>(cb, wl0, p0);
      lstm_epi_pack(acc, bias0, cs0, h0B + (size_t)sc*HB_SZ + hwoff, l15, gidx);
    }
    publish(&fh0r[bid], (unsigned)(t+1));

    // -- p1 = Whh1 @ h1[t-1] (fills the eh0 wait), then hop1 rendezvous
    v4f p1 = {0.f,0.f,0.f,0.f};
    {
      const char* hs = h1B + (size_t)sp*HB_SZ + aoffH;
      const char* cb[4] = { hs, hs+512, hs+1024, hs+1536 };
      p1 = gemm_phase<4>(cb, wl1r, p1);
      if (lead_h0) scan256_pub(fh0r, eh0, (unsigned)(t+1));
      else         wait_word(eh0, (unsigned)(t+1));
    }

    // -- L1 input part + fused next-step L0 recurrent (shared A) -> h1[t]
    {
      const char* hs = h0B + (size_t)sc*HB_SZ + aoffH;
      const char* cb[4] = { hs, hs+512, hs+1024, hs+1536 };
      v4f np0 = {0.f,0.f,0.f,0.f};
      gemm_dual4(cb, wl1, wl0r, p1, np0);
      lstm_epi_pack(p1, bias1, cs1, h1B + (size_t)sc*HB_SZ + hwoff, l15, gidx);
      p0 = np0;
    }
    publish(&fh1r[bid], (unsigned)(t+1));

    // -- hop2: fh1 rendezvous (leaders 8..15 scan; others poll eh1)
    if (lead_h1) scan256_pub(fh1r, eh1, (unsigned)(t+1));
    else         wait_word(eh1, (unsigned)(t+1));

    // -- FC (all blocks, 2 dims each): y[t] cols 2*bid..2*bid+1
    float yv[4];
    {
      const char* f1 = h1B + (size_t)sc*HB_SZ + aoffH;
      const char* cb[4] = { f1, f1+512, f1+1024, f1+1536 };
      v4f acc = {0.f,0.f,0.f,0.f};
      acc = gemm_phase<4>(cb, wlf, acc);
      char* ydst = yB + (size_t)sc*YB_SZ;
      #pragma unroll
      for (int r = 0; r < 4; r++){
        float v = fmaxf(acc[r] + biasf, 0.f);
        yv[r] = v;
        int b = rb + r;
        // y fp16 pair store (dims 2*bid, 2*bid+1) by l15==0 lanes
        unsigned int uv = (unsigned int)__builtin_bit_cast(unsigned short, (_Float16)v);
        unsigned int o1 = (unsigned int)__shfl_xor((int)uv, 1);
        if (l15 == 0){
          unsigned int pr = uv | (o1 << 16);
          ast4(ydst + ((size_t)b*ODIM + bid*2)*2, pr);
        }
      }
    }
    publish(&fyr[bid], (unsigned)(t+1));

    // -- out stores AFTER the fy publish: consumed by nobody in-kernel;
    //    retire under the next step's L0 gemm instead of on hop 3's drain.
    #pragma unroll
    for (int r = 0; r < 4; r++){
      int b = rb + r;
      if (l15 < 2) out[((size_t)b*SEQL + t)*ODIM + bid*2 + l15] = yv[r];
    }
  }
}

extern "C" void kernel_launch(void* const* d_in, const int* in_sizes, int n_in,
                              void* d_out, int out_size, void* d_ws, size_t ws_size,
                              hipStream_t stream){
  (void)in_sizes; (void)n_in; (void)out_size;

  int D = 16;
  while (D > 2 && (size_t)D*(YB_SZ + 2*HB_SZ) + FLG_BYTES > ws_size) D >>= 1;
  if ((size_t)D*(YB_SZ + 2*HB_SZ) + FLG_BYTES > ws_size) return;

  char* ws  = (char*)d_ws;
  char* yB  = ws;
  char* h0B = yB + (size_t)D*YB_SZ;
  char* h1B = h0B + (size_t)D*HB_SZ;
  char* flg = h1B + (size_t)D*HB_SZ;

  const float* h0   = (const float*)d_in[1];
  const float* c0   = (const float*)d_in[2];
  const float* Wih0 = (const float*)d_in[3];
  const float* Whh0 = (const float*)d_in[4];
  const float* bih0 = (const float*)d_in[5];
  const float* bhh0 = (const float*)d_in[6];
  const float* Wih1 = (const float*)d_in[7];
  const float* Whh1 = (const float*)d_in[8];
  const float* bih1 = (const float*)d_in[9];
  const float* bhh1 = (const float*)d_in[10];
  const float* Wfc  = (const float*)d_in[11];
  const float* bfc  = (const float*)d_in[12];
  float* out = (float*)d_out;

  (void)hipMemsetAsync(flg, 0, FLG_BYTES, stream);
  hipLaunchKernelGGL(init_kernel, dim3(256), dim3(256), 0, stream,
                     h0,
                     (_Float16*)(h0B + (size_t)(D-1)*HB_SZ),
                     (_Float16*)(h1B + (size_t)(D-1)*HB_SZ),
                     (_Float16*)(yB  + (size_t)(D-1)*YB_SZ));

  (void)hipFuncSetAttribute((const void*)decoder_kernel,
                            hipFuncAttributeMaxDynamicSharedMemorySize, SMEM_BYTES);
  hipLaunchKernelGGL(decoder_kernel, dim3(NBLK), dim3(NTHR), SMEM_BYTES, stream,
                     Wih0, Whh0, bih0, bhh0, Wih1, Whh1, bih1, bhh1,
                     Wfc, bfc, c0, out, yB, h0B, h1B, flg, D - 1);
}